// Round 1
// baseline (1486.024 us; speedup 1.0000x reference)
//
#include <hip/hip_runtime.h>

#define NN 100000
#define EE 1600000
#define DD 128
#define GG 128
#define CC 10
#define TOT (EE + NN)
#define NB_SCAN 98  // ceil(NN/1024)

// ---------- CSR build ----------
__global__ void k_count(const int* __restrict__ col, int* __restrict__ cnt) {
    int e = blockIdx.x * blockDim.x + threadIdx.x;
    if (e < EE) atomicAdd(&cnt[col[e]], 1);
}

__global__ void k_dis(const int* __restrict__ cnt, float* __restrict__ dis) {
    int n = blockIdx.x * blockDim.x + threadIdx.x;
    if (n < NN) dis[n] = rsqrtf((float)(cnt[n] + 1));  // +1 self-loop; deg>=1 always
}

__global__ void k_scan1(const int* __restrict__ cnt, int* __restrict__ offs, int* __restrict__ bsums) {
    __shared__ int s[256];
    int t = threadIdx.x;
    int base = blockIdx.x * 1024;
    int v[4];
    int tsum = 0;
#pragma unroll
    for (int j = 0; j < 4; j++) {
        int idx = base + t * 4 + j;
        v[j] = (idx < NN) ? (cnt[idx] + 1) : 0;  // +1 for self-loop slot
        tsum += v[j];
    }
    s[t] = tsum;
    __syncthreads();
    for (int off = 1; off < 256; off <<= 1) {
        int x = 0;
        if (t >= off) x = s[t - off];
        __syncthreads();
        if (t >= off) s[t] += x;
        __syncthreads();
    }
    int run = s[t] - tsum;  // exclusive prefix of this thread
#pragma unroll
    for (int j = 0; j < 4; j++) {
        int idx = base + t * 4 + j;
        if (idx < NN) offs[idx] = run;
        run += v[j];
    }
    if (t == 255) bsums[blockIdx.x] = s[255];
}

__global__ void k_scan2(const int* __restrict__ bsums, int* __restrict__ bexcl) {
    if (threadIdx.x == 0 && blockIdx.x == 0) {
        int run = 0;
        for (int i = 0; i < NB_SCAN; i++) { bexcl[i] = run; run += bsums[i]; }
    }
}

__global__ void k_scan3(int* __restrict__ offs, const int* __restrict__ bexcl, int* __restrict__ cursor) {
    int idx = blockIdx.x * blockDim.x + threadIdx.x;
    if (idx < NN) {
        int o = offs[idx] + bexcl[idx >> 10];
        offs[idx] = o;
        cursor[idx] = o;
    }
    if (idx == 0) offs[NN] = TOT;
}

__global__ void k_fill(const int* __restrict__ row, const int* __restrict__ col,
                       const float* __restrict__ dis, int* __restrict__ cursor,
                       int* __restrict__ src, float* __restrict__ nrm) {
    int i = blockIdx.x * blockDim.x + threadIdx.x;
    if (i < EE) {
        int r = row[i], c = col[i];
        int p = atomicAdd(&cursor[c], 1);
        src[p] = r;
        nrm[p] = dis[r] * dis[c];
    } else if (i < TOT) {
        int n = i - EE;
        int p = atomicAdd(&cursor[n], 1);
        src[p] = n;
        float d = dis[n];
        nrm[p] = d * d;
    }
}

// ---------- per-layer GEMM: C = A @ W, A [NN,128], W [128,128] ----------
__global__ __launch_bounds__(256) void k_gemm(const float* __restrict__ A,
                                              const float* __restrict__ W,
                                              float* __restrict__ Cout) {
    __shared__ float sW[128 * 128];   // 64 KiB
    __shared__ float sA[16 * 128];    // 8 KiB
    for (int i = threadIdx.x; i < 4096; i += 256)
        ((float4*)sW)[i] = ((const float4*)W)[i];
    int r0 = blockIdx.x * 16;
    for (int i = threadIdx.x; i < 512; i += 256) {
        int rr = r0 + (i >> 5);
        ((float4*)sA)[i] = (rr < NN) ? ((const float4*)A)[(size_t)rr * 32 + (i & 31)]
                                     : make_float4(0.f, 0.f, 0.f, 0.f);
    }
    __syncthreads();
    int lr = threadIdx.x >> 4;        // 0..15  local row
    int c  = (threadIdx.x & 15) * 8;  // col base
    float acc[8] = {0, 0, 0, 0, 0, 0, 0, 0};
    for (int k = 0; k < 128; k++) {
        float a = sA[lr * 128 + k];
        float4 w0 = *(const float4*)&sW[k * 128 + c];
        float4 w1 = *(const float4*)&sW[k * 128 + c + 4];
        acc[0] += a * w0.x; acc[1] += a * w0.y; acc[2] += a * w0.z; acc[3] += a * w0.w;
        acc[4] += a * w1.x; acc[5] += a * w1.y; acc[6] += a * w1.z; acc[7] += a * w1.w;
    }
    int r = r0 + lr;
    if (r < NN) {
        float4* o = (float4*)&Cout[(size_t)r * 128 + c];
        o[0] = make_float4(acc[0], acc[1], acc[2], acc[3]);
        o[1] = make_float4(acc[4], acc[5], acc[6], acc[7]);
    }
}

// ---------- aggregation + bias + BN + LeakyReLU ----------
__global__ __launch_bounds__(256) void k_agg(const float* __restrict__ hin,
                                             const int* __restrict__ offs,
                                             const int* __restrict__ src,
                                             const float* __restrict__ nrm,
                                             const float* __restrict__ bc,
                                             const float* __restrict__ bn_mean,
                                             const float* __restrict__ bn_var,
                                             const float* __restrict__ bn_gamma,
                                             const float* __restrict__ bn_beta,
                                             int use_bn,
                                             float* __restrict__ hout) {
    int n = blockIdx.x * 2 + (threadIdx.x >> 7);
    int d = threadIdx.x & 127;
    if (n >= NN) return;
    int e0 = offs[n], e1 = offs[n + 1];
    float acc = 0.f;
    for (int e = e0; e < e1; e++) {
        acc += hin[(size_t)src[e] * 128 + d] * nrm[e];
    }
    acc += bc[d];
    if (use_bn) {
        acc = (acc - bn_mean[d]) * rsqrtf(bn_var[d] + 1e-5f) * bn_gamma[d] + bn_beta[d];
    }
    acc = acc > 0.f ? acc : 0.03f * acc;
    hout[(size_t)n * 128 + d] = acc;
}

// ---------- global mean pool (batch is sorted) ----------
#define PN 128
__global__ __launch_bounds__(128) void k_pool(const float* __restrict__ h,
                                              const int* __restrict__ batch,
                                              float* __restrict__ pooled,
                                              float* __restrict__ counts) {
    int d = threadIdx.x;
    int n0 = blockIdx.x * PN;
    if (n0 >= NN) return;
    int n1 = n0 + PN;
    if (n1 > NN) n1 = NN;
    float acc = 0.f, cnt = 0.f;
    int g = batch[n0];
    for (int n = n0; n < n1; n++) {
        int bg = batch[n];
        if (bg != g) {
            atomicAdd(&pooled[g * 128 + d], acc);
            if (d == 0) atomicAdd(&counts[g], cnt);
            acc = 0.f; cnt = 0.f; g = bg;
        }
        acc += h[(size_t)n * 128 + d];
        cnt += 1.f;
    }
    atomicAdd(&pooled[g * 128 + d], acc);
    if (d == 0) atomicAdd(&counts[g], cnt);
}

// ---------- head: out[g,c] = (pooled[g]/cnt) . lin_w[c] + lin_b[c] ----------
__global__ void k_head(const float* __restrict__ pooled, const float* __restrict__ counts,
                       const float* __restrict__ w, const float* __restrict__ b,
                       float* __restrict__ out) {
    int i = blockIdx.x * blockDim.x + threadIdx.x;
    if (i >= GG * CC) return;
    int g = i / CC, c = i % CC;
    float cnt = counts[g];
    cnt = cnt > 1.f ? cnt : 1.f;
    float inv = 1.f / cnt;
    const float* p = &pooled[g * 128];
    const float* ww = &w[c * 128];
    float acc = 0.f;
    for (int d = 0; d < 128; d++) acc += p[d] * ww[d];
    out[i] = acc * inv + b[c];
}

extern "C" void kernel_launch(void* const* d_in, const int* in_sizes, int n_in,
                              void* d_out, int out_size, void* d_ws, size_t ws_size,
                              hipStream_t stream) {
    const float* x     = (const float*)d_in[0];
    const int*   ei    = (const int*)d_in[1];
    const int*   row   = ei;
    const int*   col   = ei + EE;
    const int*   batch = (const int*)d_in[2];
    const float* Wc    = (const float*)d_in[3];
    const float* bc    = (const float*)d_in[4];
    const float* gamma = (const float*)d_in[5];
    const float* beta  = (const float*)d_in[6];
    const float* mean  = (const float*)d_in[7];
    const float* var   = (const float*)d_in[8];
    const float* lw    = (const float*)d_in[9];
    const float* lb    = (const float*)d_in[10];
    float* out = (float*)d_out;

    char* p = (char*)d_ws;
    auto alloc = [&](size_t bytes) -> char* {
        char* r = p;
        p += (bytes + 255) & ~(size_t)255;
        return r;
    };
    int*   cnt    = (int*)alloc((size_t)NN * 4);
    float* dis    = (float*)alloc((size_t)NN * 4);
    int*   offs   = (int*)alloc((size_t)(NN + 1) * 4);
    int*   cursor = (int*)alloc((size_t)NN * 4);
    int*   bsums  = (int*)alloc((size_t)NB_SCAN * 4);
    int*   bexcl  = (int*)alloc((size_t)NB_SCAN * 4);
    int*   src    = (int*)alloc((size_t)TOT * 4);
    float* nrm    = (float*)alloc((size_t)TOT * 4);
    float* h0     = (float*)alloc((size_t)NN * 128 * 4);
    float* h1     = (float*)alloc((size_t)NN * 128 * 4);
    float* pooled = (float*)alloc((size_t)GG * 128 * 4);
    float* counts = (float*)alloc((size_t)GG * 4);

    hipMemsetAsync(cnt, 0, (size_t)NN * 4, stream);
    hipMemsetAsync(pooled, 0, (size_t)GG * 128 * 4, stream);
    hipMemsetAsync(counts, 0, (size_t)GG * 4, stream);

    k_count<<<(EE + 255) / 256, 256, 0, stream>>>(col, cnt);
    k_dis<<<(NN + 255) / 256, 256, 0, stream>>>(cnt, dis);
    k_scan1<<<NB_SCAN, 256, 0, stream>>>(cnt, offs, bsums);
    k_scan2<<<1, 64, 0, stream>>>(bsums, bexcl);
    k_scan3<<<(NN + 255) / 256, 256, 0, stream>>>(offs, bexcl, cursor);
    k_fill<<<(TOT + 255) / 256, 256, 0, stream>>>(row, col, dis, cursor, src, nrm);

    const float* hin = x;
    for (int l = 0; l < 3; l++) {
        int bnidx = (l < 2) ? l : 0;  // avoid OOB read when BN unused
        k_gemm<<<(NN + 15) / 16, 256, 0, stream>>>(hin, Wc + (size_t)l * 16384, h0);
        k_agg<<<(NN + 1) / 2, 256, 0, stream>>>(h0, offs, src, nrm,
                                                bc + l * 128,
                                                mean + bnidx * 128, var + bnidx * 128,
                                                gamma + bnidx * 128, beta + bnidx * 128,
                                                (l < 2) ? 1 : 0, h1);
        hin = h1;
    }
    k_pool<<<(NN + PN - 1) / PN, 128, 0, stream>>>(h1, batch, pooled, counts);
    k_head<<<(GG * CC + 255) / 256, 256, 0, stream>>>(pooled, counts, lw, lb, out);
}

// Round 2
// 537.788 us; speedup vs baseline: 2.7632x; 2.7632x over previous
//
#include <hip/hip_runtime.h>
#include <hip/hip_bf16.h>

#define NN 100000
#define EE 1600000
#define DD 128
#define GG 128
#define CC 10
#define TOT (EE + NN)
#define NB_SCAN 98  // ceil(NN/1024)

typedef __attribute__((ext_vector_type(8))) short bf16x8;
typedef __attribute__((ext_vector_type(4))) float f32x4;
typedef unsigned int u32;

__device__ inline float blo(u32 u) { return __uint_as_float(u << 16); }
__device__ inline float bhi(u32 u) { return __uint_as_float(u & 0xffff0000u); }
// pack two floats to bf16x2 (RNE)
__device__ inline u32 bpack(float x, float y) {
    u32 bx = __float_as_uint(x);
    u32 by = __float_as_uint(y);
    bx = (bx + 0x7fffu + ((bx >> 16) & 1u)) >> 16;
    by = (by + 0x7fffu + ((by >> 16) & 1u)) & 0xffff0000u;
    return bx | by;
}

// ---------- CSR build ----------
__global__ void k_count(const int* __restrict__ col, int* __restrict__ cnt) {
    int e = blockIdx.x * blockDim.x + threadIdx.x;
    if (e < EE) atomicAdd(&cnt[col[e]], 1);
}

__global__ void k_dis(const int* __restrict__ cnt, float* __restrict__ dis) {
    int n = blockIdx.x * blockDim.x + threadIdx.x;
    if (n < NN) dis[n] = rsqrtf((float)(cnt[n] + 1));  // +1 self-loop
}

__global__ void k_scan1(const int* __restrict__ cnt, int* __restrict__ offs, int* __restrict__ bsums) {
    __shared__ int s[256];
    int t = threadIdx.x;
    int base = blockIdx.x * 1024;
    int v[4];
    int tsum = 0;
#pragma unroll
    for (int j = 0; j < 4; j++) {
        int idx = base + t * 4 + j;
        v[j] = (idx < NN) ? (cnt[idx] + 1) : 0;
        tsum += v[j];
    }
    s[t] = tsum;
    __syncthreads();
    for (int off = 1; off < 256; off <<= 1) {
        int x = 0;
        if (t >= off) x = s[t - off];
        __syncthreads();
        if (t >= off) s[t] += x;
        __syncthreads();
    }
    int run = s[t] - tsum;
#pragma unroll
    for (int j = 0; j < 4; j++) {
        int idx = base + t * 4 + j;
        if (idx < NN) offs[idx] = run;
        run += v[j];
    }
    if (t == 255) bsums[blockIdx.x] = s[255];
}

__global__ void k_scan2(const int* __restrict__ bsums, int* __restrict__ bexcl) {
    if (threadIdx.x == 0 && blockIdx.x == 0) {
        int run = 0;
        for (int i = 0; i < NB_SCAN; i++) { bexcl[i] = run; run += bsums[i]; }
    }
}

__global__ void k_scan3(int* __restrict__ offs, const int* __restrict__ bexcl, int* __restrict__ cursor) {
    int idx = blockIdx.x * blockDim.x + threadIdx.x;
    if (idx < NN) {
        int o = offs[idx] + bexcl[idx >> 10];
        offs[idx] = o;
        cursor[idx] = o;
    }
    if (idx == 0) offs[NN] = TOT;
}

__global__ void k_fill(const int* __restrict__ row, const int* __restrict__ col,
                       const float* __restrict__ dis, int* __restrict__ cursor,
                       int* __restrict__ src, float* __restrict__ nrm) {
    int i = blockIdx.x * blockDim.x + threadIdx.x;
    if (i < EE) {
        int r = row[i], c = col[i];
        int p = atomicAdd(&cursor[c], 1);
        src[p] = r;
        nrm[p] = dis[r] * dis[c];
    } else if (i < TOT) {
        int n = i - EE;
        int p = atomicAdd(&cursor[n], 1);
        src[p] = n;
        float d = dis[n];
        nrm[p] = d * d;
    }
}

// ---------- params prep: W^T -> bf16, fold bias+BN into scale/offset ----------
__global__ void k_prep(const float* __restrict__ Wc, const float* __restrict__ bc,
                       const float* __restrict__ gamma, const float* __restrict__ beta,
                       const float* __restrict__ mean, const float* __restrict__ var,
                       __hip_bfloat16* __restrict__ WT,
                       float* __restrict__ sc, float* __restrict__ tc) {
    int i = blockIdx.x * 256 + threadIdx.x;
    if (i < 3 * 128) {
        int l = i >> 7, d = i & 127;
        float s, t;
        if (l < 2) {
            float rs = rsqrtf(var[l * 128 + d] + 1e-5f);
            s = gamma[l * 128 + d] * rs;
            t = (bc[l * 128 + d] - mean[l * 128 + d]) * s + beta[l * 128 + d];
        } else {
            s = 1.f;
            t = bc[2 * 128 + d];
        }
        sc[i] = s; tc[i] = t;
    }
    if (i < 3 * 16384) {
        int l = i >> 14, r = (i >> 7) & 127, k = i & 127;
        WT[i] = __float2bfloat16(Wc[l * 16384 + k * 128 + r]);  // WT[l][r][k] = W[l][k][r]
    }
}

// ---------- GEMM: C[N,128] = A[N,128] @ W, bf16 MFMA, WT is W^T bf16 ----------
// Per 256-thread block: 4 waves x 16 rows = 64 rows, full 128 cols.
template <int FP32IN>
__global__ __launch_bounds__(256) void k_gemm(const void* __restrict__ Ain,
                                              const __hip_bfloat16* __restrict__ WT,
                                              __hip_bfloat16* __restrict__ Cout) {
    int wave = threadIdx.x >> 6, lane = threadIdx.x & 63;
    int lg = lane >> 4, lr = lane & 15;
    int r0w = blockIdx.x * 64 + wave * 16;
    f32x4 zero = {0.f, 0.f, 0.f, 0.f};
    f32x4 acc[8];
#pragma unroll
    for (int ct = 0; ct < 8; ct++) acc[ct] = zero;

    int arow = r0w + lr;
    if (arow > NN - 1) arow = NN - 1;

#pragma unroll
    for (int kk = 0; kk < 4; kk++) {
        bf16x8 a;
        if (FP32IN) {
            const float* ap = (const float*)Ain + (size_t)arow * 128 + kk * 32 + lg * 8;
            float4 f0 = *(const float4*)ap;
            float4 f1 = *(const float4*)(ap + 4);
            u32 t0 = bpack(f0.x, f0.y), t1 = bpack(f0.z, f0.w);
            u32 t2 = bpack(f1.x, f1.y), t3 = bpack(f1.z, f1.w);
            uint4 t = make_uint4(t0, t1, t2, t3);
            a = *(bf16x8*)&t;
        } else {
            a = *(const bf16x8*)((const __hip_bfloat16*)Ain + (size_t)arow * 128 + kk * 32 + lg * 8);
        }
#pragma unroll
        for (int ct = 0; ct < 8; ct++) {
            bf16x8 b = *(const bf16x8*)(WT + (size_t)(ct * 16 + lr) * 128 + kk * 32 + lg * 8);
            acc[ct] = __builtin_amdgcn_mfma_f32_16x16x32_bf16(a, b, acc[ct], 0, 0, 0);
        }
    }
    // C/D layout: col = lane&15, row = (lane>>4)*4 + reg
#pragma unroll
    for (int ct = 0; ct < 8; ct++) {
#pragma unroll
        for (int r = 0; r < 4; r++) {
            int row = r0w + lg * 4 + r;
            if (row < NN) Cout[(size_t)row * 128 + ct * 16 + lr] = __float2bfloat16(acc[ct][r]);
        }
    }
}

// ---------- aggregation + fused scale/offset + LeakyReLU (bf16 in/out) ----------
// one 64-lane wave per node; lane covers 2 feature cols via bf16x2 (u32) loads
__global__ __launch_bounds__(256) void k_agg(const u32* __restrict__ hin,
                                             const int* __restrict__ offs,
                                             const int* __restrict__ src,
                                             const float* __restrict__ nrm,
                                             const float* __restrict__ sc,
                                             const float* __restrict__ tc,
                                             u32* __restrict__ hout) {
    int node = (blockIdx.x << 2) + (threadIdx.x >> 6);
    int lane = threadIdx.x & 63;
    if (node >= NN) return;
    int e0 = offs[node], e1 = offs[node + 1];
    float a0 = 0.f, a1 = 0.f;
    int e = e0;
    for (; e + 4 <= e1; e += 4) {
        int s0 = src[e], s1 = src[e + 1], s2 = src[e + 2], s3 = src[e + 3];
        float w0 = nrm[e], w1 = nrm[e + 1], w2 = nrm[e + 2], w3 = nrm[e + 3];
        u32 u0 = hin[(u32)s0 * 64u + lane];
        u32 u1 = hin[(u32)s1 * 64u + lane];
        u32 u2 = hin[(u32)s2 * 64u + lane];
        u32 u3 = hin[(u32)s3 * 64u + lane];
        a0 += blo(u0) * w0; a1 += bhi(u0) * w0;
        a0 += blo(u1) * w1; a1 += bhi(u1) * w1;
        a0 += blo(u2) * w2; a1 += bhi(u2) * w2;
        a0 += blo(u3) * w3; a1 += bhi(u3) * w3;
    }
    for (; e < e1; e++) {
        int s = src[e];
        float w = nrm[e];
        u32 u = hin[(u32)s * 64u + lane];
        a0 += blo(u) * w; a1 += bhi(u) * w;
    }
    int d0 = lane * 2;
    float r0 = a0 * sc[d0] + tc[d0];
    float r1 = a1 * sc[d0 + 1] + tc[d0 + 1];
    r0 = r0 > 0.f ? r0 : 0.03f * r0;
    r1 = r1 > 0.f ? r1 : 0.03f * r1;
    hout[(u32)node * 64u + lane] = bpack(r0, r1);
}

// ---------- global mean pool (batch sorted), bf16 input ----------
#define PN 128
__global__ __launch_bounds__(64) void k_pool(const u32* __restrict__ h,
                                             const int* __restrict__ batch,
                                             float* __restrict__ pooled,
                                             float* __restrict__ counts) {
    int lane = threadIdx.x;  // 0..63, covers 2 cols
    int n0 = blockIdx.x * PN;
    if (n0 >= NN) return;
    int n1 = n0 + PN;
    if (n1 > NN) n1 = NN;
    float a0 = 0.f, a1 = 0.f, cnt = 0.f;
    int g = batch[n0];
    for (int n = n0; n < n1; n++) {
        int bg = batch[n];
        if (bg != g) {
            atomicAdd(&pooled[g * 128 + lane * 2], a0);
            atomicAdd(&pooled[g * 128 + lane * 2 + 1], a1);
            if (lane == 0) atomicAdd(&counts[g], cnt);
            a0 = 0.f; a1 = 0.f; cnt = 0.f; g = bg;
        }
        u32 u = h[(u32)n * 64u + lane];
        a0 += blo(u); a1 += bhi(u);
        cnt += 1.f;
    }
    atomicAdd(&pooled[g * 128 + lane * 2], a0);
    atomicAdd(&pooled[g * 128 + lane * 2 + 1], a1);
    if (lane == 0) atomicAdd(&counts[g], cnt);
}

// ---------- head ----------
__global__ void k_head(const float* __restrict__ pooled, const float* __restrict__ counts,
                       const float* __restrict__ w, const float* __restrict__ b,
                       float* __restrict__ out) {
    int i = blockIdx.x * blockDim.x + threadIdx.x;
    if (i >= GG * CC) return;
    int g = i / CC, c = i % CC;
    float cnt = counts[g];
    cnt = cnt > 1.f ? cnt : 1.f;
    float inv = 1.f / cnt;
    const float* p = &pooled[g * 128];
    const float* ww = &w[c * 128];
    float acc = 0.f;
    for (int d = 0; d < 128; d++) acc += p[d] * ww[d];
    out[i] = acc * inv + b[c];
}

extern "C" void kernel_launch(void* const* d_in, const int* in_sizes, int n_in,
                              void* d_out, int out_size, void* d_ws, size_t ws_size,
                              hipStream_t stream) {
    const float* x     = (const float*)d_in[0];
    const int*   ei    = (const int*)d_in[1];
    const int*   row   = ei;
    const int*   col   = ei + EE;
    const int*   batch = (const int*)d_in[2];
    const float* Wc    = (const float*)d_in[3];
    const float* bc    = (const float*)d_in[4];
    const float* gamma = (const float*)d_in[5];
    const float* beta  = (const float*)d_in[6];
    const float* mean  = (const float*)d_in[7];
    const float* var   = (const float*)d_in[8];
    const float* lw    = (const float*)d_in[9];
    const float* lb    = (const float*)d_in[10];
    float* out = (float*)d_out;

    char* p = (char*)d_ws;
    auto alloc = [&](size_t bytes) -> char* {
        char* r = p;
        p += (bytes + 255) & ~(size_t)255;
        return r;
    };
    int*   cnt    = (int*)alloc((size_t)NN * 4);
    float* dis    = (float*)alloc((size_t)NN * 4);
    int*   offs   = (int*)alloc((size_t)(NN + 1) * 4);
    int*   cursor = (int*)alloc((size_t)NN * 4);
    int*   bsums  = (int*)alloc((size_t)NB_SCAN * 4);
    int*   bexcl  = (int*)alloc((size_t)NB_SCAN * 4);
    int*   src    = (int*)alloc((size_t)TOT * 4);
    float* nrm    = (float*)alloc((size_t)TOT * 4);
    __hip_bfloat16* WT = (__hip_bfloat16*)alloc((size_t)3 * 16384 * 2);
    float* sc     = (float*)alloc((size_t)3 * 128 * 4);
    float* tc     = (float*)alloc((size_t)3 * 128 * 4);
    __hip_bfloat16* h0b = (__hip_bfloat16*)alloc((size_t)NN * 128 * 2);
    __hip_bfloat16* h1b = (__hip_bfloat16*)alloc((size_t)NN * 128 * 2);
    float* pooled = (float*)alloc((size_t)GG * 128 * 4);
    float* counts = (float*)alloc((size_t)GG * 4);

    hipMemsetAsync(cnt, 0, (size_t)NN * 4, stream);
    hipMemsetAsync(pooled, 0, (size_t)GG * 128 * 4, stream);
    hipMemsetAsync(counts, 0, (size_t)GG * 4, stream);

    k_count<<<(EE + 255) / 256, 256, 0, stream>>>(col, cnt);
    k_dis<<<(NN + 255) / 256, 256, 0, stream>>>(cnt, dis);
    k_scan1<<<NB_SCAN, 256, 0, stream>>>(cnt, offs, bsums);
    k_scan2<<<1, 64, 0, stream>>>(bsums, bexcl);
    k_scan3<<<(NN + 255) / 256, 256, 0, stream>>>(offs, bexcl, cursor);
    k_fill<<<(TOT + 255) / 256, 256, 0, stream>>>(row, col, dis, cursor, src, nrm);
    k_prep<<<192, 256, 0, stream>>>(Wc, bc, gamma, beta, mean, var, WT, sc, tc);

    const int gemm_grid = (NN + 63) / 64;
    const int agg_grid  = (NN + 3) / 4;

    // layer 0: A = x (fp32)
    k_gemm<1><<<gemm_grid, 256, 0, stream>>>((const void*)x, WT, h0b);
    k_agg<<<agg_grid, 256, 0, stream>>>((const u32*)h0b, offs, src, nrm, sc, tc, (u32*)h1b);
    // layer 1
    k_gemm<0><<<gemm_grid, 256, 0, stream>>>((const void*)h1b, WT + 16384, h0b);
    k_agg<<<agg_grid, 256, 0, stream>>>((const u32*)h0b, offs, src, nrm, sc + 128, tc + 128, (u32*)h1b);
    // layer 2
    k_gemm<0><<<gemm_grid, 256, 0, stream>>>((const void*)h1b, WT + 2 * 16384, h0b);
    k_agg<<<agg_grid, 256, 0, stream>>>((const u32*)h0b, offs, src, nrm, sc + 256, tc + 256, (u32*)h1b);

    k_pool<<<(NN + PN - 1) / PN, 64, 0, stream>>>((const u32*)h1b, batch, pooled, counts);
    k_head<<<(GG * CC + 255) / 256, 256, 0, stream>>>(pooled, counts, lw, lb, out);
}